// Round 3
// baseline (727.904 us; speedup 1.0000x reference)
//
#include <hip/hip_runtime.h>

#define B_ 512
#define L_ 512
#define N_ 128
#define C_BIAS 3.0f

typedef _Float16 h2_t __attribute__((ext_vector_type(2)));

__device__ __forceinline__ float dot2f(h2_t a, h2_t b, float c) {
#if __has_builtin(__builtin_amdgcn_fdot2)
    return __builtin_amdgcn_fdot2(a, b, c, false);
#else
    return c + (float)a[0] * (float)b[0] + (float)a[1] * (float)b[1];
#endif
}

// ---------------------------------------------------------------------------
// norm_kernel: ONE WAVE (64 threads) per batch -> wave-synchronous, zero
// s_barrier, zero vmcnt(0) drains. Lane l owns states j0=2l, j1=2l+1.
// ET columns for both states live in registers (et0/et1, 64 h2 each) for all
// 512 steps. Per step:
//   - read E_{t-1} (128 f16 = 256B, broadcast ds_read_b128 x16)
//   - 128 v_dot2_f32_f16 -> full column sums s0,s1 (no cross-lane combine)
//   - lagged 6-level shfl max of ns_{t-1} overlaps the dot phase
//   - nxt = log(s) + M_norm + C + em ; mask-select ; E_t = exp(ns - M_new - C)
// Emission prefetched distance-4 via a manually unrolled 4-slot register pipe
// (~1400cyc cover, no barrier ever drains it). Mask row staged in LDS once.
// Path score for the batch folded into the preamble.
// ---------------------------------------------------------------------------
__global__ __launch_bounds__(64) void norm_kernel(
    const float* __restrict__ em, const int* __restrict__ tg,
    const float* __restrict__ mask, const float* __restrict__ st,
    const float* __restrict__ trans,
    float* __restrict__ norm_out, float* __restrict__ path_out)
{
    __shared__ __align__(16) h2_t Eh[64];      // E vector, 128 f16
    __shared__ float Mlds[L_];                 // mask row

    const int l = threadIdx.x;
    const int b = blockIdx.x;
    const size_t base = (size_t)b * L_ * N_;

    // ---- path score (one wave) ----
    float pacc = 0.f;
    for (int t = 1 + l; t < L_; t += 64) {
        int cur  = tg[b * L_ + t];
        int prev = tg[b * L_ + t - 1];
        pacc += mask[b * L_ + t] * (trans[prev * N_ + cur] + em[base + (size_t)t * N_ + cur]);
    }
#pragma unroll
    for (int off = 32; off >= 1; off >>= 1) pacc += __shfl_xor(pacc, off);
    if (l == 0) {
        int t0 = tg[b * L_];
        path_out[b] = pacc + st[t0] + em[base + t0];
    }

    // ---- stage mask row in LDS ----
#pragma unroll
    for (int k = 0; k < 8; ++k) Mlds[l + 64 * k] = mask[b * L_ + l + 64 * k];

    // ---- ET columns into registers: et0/et1[k] = (ET[2k][j],ET[2k+1][j]) ----
    h2_t et0[64], et1[64];
#pragma unroll
    for (int k = 0; k < 64; ++k) {
        float2 r0 = *(const float2*)(trans + (2 * k    ) * N_ + 2 * l);
        float2 r1 = *(const float2*)(trans + (2 * k + 1) * N_ + 2 * l);
        h2_t a, c;
        a[0] = (_Float16)__expf(r0.x); a[1] = (_Float16)__expf(r1.x);
        c[0] = (_Float16)__expf(r0.y); c[1] = (_Float16)__expf(r1.y);
        et0[k] = a; et1[k] = c;
    }

    // ---- init: ns_0, exact max, E_0 ----
    float2 e0v = *(const float2*)(em + base + 2 * l);
    float ns0 = st[2 * l]     + e0v.x;
    float ns1 = st[2 * l + 1] + e0v.y;
    float M_norm;
    {
        float mx = fmaxf(ns0, ns1);
#pragma unroll
        for (int off = 32; off >= 1; off >>= 1) mx = fmaxf(mx, __shfl_xor(mx, off));
        M_norm = mx;
    }
    {
        h2_t eo;
        eo[0] = (_Float16)__expf(ns0 - M_norm - C_BIAS);
        eo[1] = (_Float16)__expf(ns1 - M_norm - C_BIAS);
        Eh[l] = eo;
    }

    // ---- emission prefetch pipe, distance 4 ----
    float2 pipe0 = *(const float2*)(em + base + (size_t)1 * N_ + 2 * l);
    float2 pipe1 = *(const float2*)(em + base + (size_t)2 * N_ + 2 * l);
    float2 pipe2 = *(const float2*)(em + base + (size_t)3 * N_ + 2 * l);
    float2 pipe3 = *(const float2*)(em + base + (size_t)4 * N_ + 2 * l);

    auto step = [&](int t, float2& slot) {
        float2 emv = slot;
        int tpf = t + 4; if (tpf > L_ - 1) tpf = L_ - 1;
        slot = *(const float2*)(em + base + (size_t)tpf * N_ + 2 * l);
        float mk = Mlds[t];

        // lagged max of ns_{t-1} (overlaps dot issue)
        float mx = fmaxf(ns0, ns1);
#pragma unroll
        for (int off = 32; off >= 1; off >>= 1) mx = fmaxf(mx, __shfl_xor(mx, off));

        // dot: s_j = sum_i E[i]*ET[i][j], full 128-i sums per lane
        float a0 = 0.f, a1 = 0.f, a2 = 0.f, a3 = 0.f;
        float c0 = 0.f, c1 = 0.f, c2 = 0.f, c3 = 0.f;
        const float4* E4 = (const float4*)Eh;
#pragma unroll
        for (int r = 0; r < 16; ++r) {
            float4 blk = E4[r];
            const h2_t* e2 = (const h2_t*)&blk;
            a0 = dot2f(e2[0], et0[4 * r + 0], a0);
            a1 = dot2f(e2[1], et0[4 * r + 1], a1);
            a2 = dot2f(e2[2], et0[4 * r + 2], a2);
            a3 = dot2f(e2[3], et0[4 * r + 3], a3);
            c0 = dot2f(e2[0], et1[4 * r + 0], c0);
            c1 = dot2f(e2[1], et1[4 * r + 1], c1);
            c2 = dot2f(e2[2], et1[4 * r + 2], c2);
            c3 = dot2f(e2[3], et1[4 * r + 3], c3);
        }
        float s_0 = (a0 + a1) + (a2 + a3);
        float s_1 = (c0 + c1) + (c2 + c3);

        float badd = M_norm + C_BIAS;
        float nxt0 = __logf(s_0) + badd + emv.x;
        float nxt1 = __logf(s_1) + badd + emv.y;
        float im   = 1.f - mk;
        ns0 = mk * nxt0 + im * ns0;
        ns1 = mk * nxt1 + im * ns1;

        M_norm = mx;
        h2_t eo;
        eo[0] = (_Float16)__expf(ns0 - mx - C_BIAS);
        eo[1] = (_Float16)__expf(ns1 - mx - C_BIAS);
        Eh[l] = eo;
    };

    // main loop: t = 1..508 unrolled x4, remainder 509..511
    for (int tt = 1; tt + 3 < L_; tt += 4) {
        step(tt    , pipe0);
        step(tt + 1, pipe1);
        step(tt + 2, pipe2);
        step(tt + 3, pipe3);
    }
    step(509, pipe0);
    step(510, pipe1);
    step(511, pipe2);

    // ---- final logsumexp over states ----
    float mx = fmaxf(ns0, ns1);
#pragma unroll
    for (int off = 32; off >= 1; off >>= 1) mx = fmaxf(mx, __shfl_xor(mx, off));
    float v = __expf(ns0 - mx) + __expf(ns1 - mx);
#pragma unroll
    for (int off = 32; off >= 1; off >>= 1) v += __shfl_xor(v, off);
    if (l == 0) norm_out[b] = mx + __logf(v);
}

// ---------------------------------------------------------------------------
__global__ __launch_bounds__(256) void final_kernel(
    const float* __restrict__ norm, const float* __restrict__ path,
    float* __restrict__ out)
{
    const int tid = threadIdx.x;
    float v = 0.f;
    for (int i = tid; i < B_; i += 256) v += norm[i] - path[i];
#pragma unroll
    for (int off = 32; off >= 1; off >>= 1) v += __shfl_xor(v, off);
    __shared__ float red[4];
    if ((tid & 63) == 0) red[tid >> 6] = v;
    __syncthreads();
    if (tid == 0) out[0] = (red[0] + red[1] + red[2] + red[3]) / (float)B_;
}

// ---------------------------------------------------------------------------
extern "C" void kernel_launch(void* const* d_in, const int* in_sizes, int n_in,
                              void* d_out, int out_size, void* d_ws, size_t ws_size,
                              hipStream_t stream) {
    const float* emission    = (const float*)d_in[0];
    const int*   target      = (const int*)  d_in[1];
    const float* mask        = (const float*)d_in[2];
    const float* start_trans = (const float*)d_in[3];
    const float* trans       = (const float*)d_in[4];
    float* out = (float*)d_out;

    float* ws_f  = (float*)d_ws;
    float* path  = ws_f;          // 512 floats
    float* norm  = ws_f + 512;    // 512 floats

    norm_kernel <<<B_, 64, 0, stream>>>(emission, target, mask, start_trans, trans, norm, path);
    final_kernel<<<1, 256, 0, stream>>>(norm, path, out);
}

// Round 4
// 353.008 us; speedup vs baseline: 2.0620x; 2.0620x over previous
//
#include <hip/hip_runtime.h>

#define B_ 512
#define L_ 512
#define N_ 128
#define TM 256          // boundary: fwd produces alpha_255, bwd produces beta_255
#define C_BIAS 3.0f

typedef _Float16 h2_t __attribute__((ext_vector_type(2)));

__device__ __forceinline__ float dot2f(h2_t a, h2_t b, float c) {
#if __has_builtin(__builtin_amdgcn_fdot2)
    return __builtin_amdgcn_fdot2(a, b, c, false);
#else
    return c + (float)a[0] * (float)b[0] + (float)a[1] * (float)b[1];
#endif
}

// ---- full-rate VALU wave-64 reductions via DPP (no ds_swizzle chains) ----
// sequence: quad_perm[1,0,3,2], quad_perm[2,3,0,1], row_half_mirror,
// row_mirror, row_bcast15, row_bcast31 ; lane 63 holds the full result.
#define DPP_STEP_MAX(v, ctrl)                                                   \
    {                                                                           \
        int _t = __builtin_amdgcn_update_dpp(__float_as_int(v),                 \
                    __float_as_int(v), ctrl, 0xf, 0xf, false);                  \
        v = fmaxf(v, __int_as_float(_t));                                       \
    }
#define DPP_STEP_ADD(v, ctrl)                                                   \
    {                                                                           \
        int _t = __builtin_amdgcn_update_dpp(__float_as_int(v),                 \
                    __float_as_int(v), ctrl, 0xf, 0xf, false);                  \
        v = v + __int_as_float(_t);                                             \
    }

__device__ __forceinline__ float wave_max(float v) {
    DPP_STEP_MAX(v, 0xB1);   // quad_perm [1,0,3,2]
    DPP_STEP_MAX(v, 0x4E);   // quad_perm [2,3,0,1]
    DPP_STEP_MAX(v, 0x141);  // row_half_mirror
    DPP_STEP_MAX(v, 0x140);  // row_mirror
    DPP_STEP_MAX(v, 0x142);  // row_bcast15
    DPP_STEP_MAX(v, 0x143);  // row_bcast31
    return __int_as_float(__builtin_amdgcn_readlane(__float_as_int(v), 63));
}
__device__ __forceinline__ float wave_sum(float v) {
    DPP_STEP_ADD(v, 0xB1);
    DPP_STEP_ADD(v, 0x4E);
    DPP_STEP_ADD(v, 0x141);
    DPP_STEP_ADD(v, 0x140);
    DPP_STEP_ADD(v, 0x142);  // lane63 path stays exact; other lanes don't matter
    DPP_STEP_ADD(v, 0x143);
    return __int_as_float(__builtin_amdgcn_readlane(__float_as_int(v), 63));
}

// ---------------------------------------------------------------------------
// norm_kernel: 1024 blocks x 64 threads (1 wave each) = 1 wave per SIMD.
// blockIdx: b = blockIdx.x >> 1 ; bw = blockIdx.x & 1 (0 = forward, 1 = backward).
// Forward  : alpha_t[j] = m_t*(LSE_i(alpha_{t-1}[i]+T[i][j]) + em_t[j]) + (1-m_t)*alpha_{t-1}[j]
//            lane owns states j=2l,2l+1 (ET COLUMN fragments in regs).
// Backward : beta_t[i]  = m_{t+1}*(LSE_j(T[i][j]+em_{t+1}[j]+beta_{t+1}[j])) + (1-m_{t+1})*beta_{t+1}[i]
//            lane owns states i=2l,2l+1 (ET ROW fragments in regs); the LDS
//            broadcast vector is F[j]=exp(beta[j]+em[j]-M-C).
// Z_b = LSE_j(alpha_255[j] + beta_255[j])   (combined in kernel 2).
// Wave-synchronous: zero barriers, zero vmcnt(0) drains. Lagged DPP max.
// ---------------------------------------------------------------------------
__global__ __launch_bounds__(64) void norm_kernel(
    const float* __restrict__ em, const int* __restrict__ tg,
    const float* __restrict__ mask, const float* __restrict__ st,
    const float* __restrict__ trans,
    float* __restrict__ alpha, float* __restrict__ beta,
    float* __restrict__ pathf, float* __restrict__ pathb)
{
    __shared__ __align__(16) h2_t Eh[64];   // broadcast vector (E fwd / F bwd), 128 f16
    __shared__ float Mlds[TM];              // mask row half

    const int l  = threadIdx.x;
    const int b  = blockIdx.x >> 1;
    const int bw = blockIdx.x & 1;
    const size_t base = (size_t)b * L_ * N_;
    const int bL = b * L_;

    if (bw == 0) {
        // ================= FORWARD =================
        // path-score half: t in [1, TM)
        float pacc = 0.f;
        for (int t = 1 + l; t < TM; t += 64) {
            int cur  = tg[bL + t];
            int prev = tg[bL + t - 1];
            pacc += mask[bL + t] * (trans[prev * N_ + cur] + em[base + (size_t)t * N_ + cur]);
        }
        pacc = wave_sum(pacc);
        if (l == 0) {
            int t0 = tg[bL];
            pathf[b] = pacc + st[t0] + em[base + t0];
        }

#pragma unroll
        for (int k = 0; k < 4; ++k) Mlds[l + 64 * k] = mask[bL + l + 64 * k];

        // ET column fragments: et0/et1[k] = (ET[2k][j], ET[2k+1][j]) for j=2l / 2l+1
        h2_t et0[64], et1[64];
#pragma unroll
        for (int k = 0; k < 64; ++k) {
            float2 r0 = *(const float2*)(trans + (2 * k    ) * N_ + 2 * l);
            float2 r1 = *(const float2*)(trans + (2 * k + 1) * N_ + 2 * l);
            h2_t a, c;
            a[0] = (_Float16)__expf(r0.x); a[1] = (_Float16)__expf(r1.x);
            c[0] = (_Float16)__expf(r0.y); c[1] = (_Float16)__expf(r1.y);
            et0[k] = a; et1[k] = c;
        }

        // init alpha_0
        float2 e0 = *(const float2*)(em + base + 2 * l);
        float2 s2 = *(const float2*)(st + 2 * l);
        float ns0 = s2.x + e0.x;
        float ns1 = s2.y + e0.y;
        float Mprev = wave_max(fmaxf(ns0, ns1));
        {
            h2_t eo;
            eo[0] = (_Float16)__expf(ns0 - Mprev - C_BIAS);
            eo[1] = (_Float16)__expf(ns1 - Mprev - C_BIAS);
            Eh[l] = eo;
        }

        float2 pipe0 = *(const float2*)(em + base + (size_t)1 * N_ + 2 * l);
        float2 pipe1 = *(const float2*)(em + base + (size_t)2 * N_ + 2 * l);
        float2 pipe2 = *(const float2*)(em + base + (size_t)3 * N_ + 2 * l);
        float2 pipe3 = *(const float2*)(em + base + (size_t)4 * N_ + 2 * l);

        auto step = [&](int t, float2& slot) {
            float2 emv = slot;
            int tpf = t + 4; if (tpf > TM - 1) tpf = TM - 1;
            slot = *(const float2*)(em + base + (size_t)tpf * N_ + 2 * l);
            float mk = Mlds[t];

            float mx = wave_max(fmaxf(ns0, ns1));   // max(ns_{t-1}); overlaps dots

            float a0 = 0.f, a1 = 0.f, a2 = 0.f, a3 = 0.f;
            float c0 = 0.f, c1 = 0.f, c2 = 0.f, c3 = 0.f;
            const float4* E4 = (const float4*)Eh;
#pragma unroll
            for (int r = 0; r < 16; ++r) {
                float4 blk = E4[r];
                const h2_t* e2 = (const h2_t*)&blk;
                a0 = dot2f(e2[0], et0[4 * r + 0], a0);
                a1 = dot2f(e2[1], et0[4 * r + 1], a1);
                a2 = dot2f(e2[2], et0[4 * r + 2], a2);
                a3 = dot2f(e2[3], et0[4 * r + 3], a3);
                c0 = dot2f(e2[0], et1[4 * r + 0], c0);
                c1 = dot2f(e2[1], et1[4 * r + 1], c1);
                c2 = dot2f(e2[2], et1[4 * r + 2], c2);
                c3 = dot2f(e2[3], et1[4 * r + 3], c3);
            }
            float s_0 = (a0 + a1) + (a2 + a3);
            float s_1 = (c0 + c1) + (c2 + c3);

            float badd = Mprev + C_BIAS;
            float nxt0 = __logf(s_0) + badd + emv.x;
            float nxt1 = __logf(s_1) + badd + emv.y;
            float im = 1.f - mk;
            ns0 = mk * nxt0 + im * ns0;
            ns1 = mk * nxt1 + im * ns1;

            Mprev = mx;
            h2_t eo;
            eo[0] = (_Float16)__expf(ns0 - mx - C_BIAS);
            eo[1] = (_Float16)__expf(ns1 - mx - C_BIAS);
            Eh[l] = eo;
        };

        for (int tt = 1; tt + 3 < TM; tt += 4) {
            step(tt    , pipe0);
            step(tt + 1, pipe1);
            step(tt + 2, pipe2);
            step(tt + 3, pipe3);
        }
        step(TM - 3, pipe0);
        step(TM - 2, pipe1);
        step(TM - 1, pipe2);

        *(float2*)(alpha + b * N_ + 2 * l) = make_float2(ns0, ns1);
    } else {
        // ================= BACKWARD =================
        // path-score half: t in [TM, L)
        float pacc = 0.f;
        for (int t = TM + l; t < L_; t += 64) {
            int cur  = tg[bL + t];
            int prev = tg[bL + t - 1];
            pacc += mask[bL + t] * (trans[prev * N_ + cur] + em[base + (size_t)t * N_ + cur]);
        }
        pacc = wave_sum(pacc);
        if (l == 0) pathb[b] = pacc;

#pragma unroll
        for (int k = 0; k < 4; ++k) Mlds[l + 64 * k] = mask[bL + TM + l + 64 * k];

        // ET row fragments: er0/er1[k] = (ET[i][2k], ET[i][2k+1]) for i=2l / 2l+1
        h2_t er0[64], er1[64];
#pragma unroll
        for (int k4 = 0; k4 < 32; ++k4) {
            float4 q0 = *(const float4*)(trans + (2 * l    ) * N_ + 4 * k4);
            float4 q1 = *(const float4*)(trans + (2 * l + 1) * N_ + 4 * k4);
            h2_t a, c;
            a[0] = (_Float16)__expf(q0.x); a[1] = (_Float16)__expf(q0.y);
            er0[2 * k4] = a;
            a[0] = (_Float16)__expf(q0.z); a[1] = (_Float16)__expf(q0.w);
            er0[2 * k4 + 1] = a;
            c[0] = (_Float16)__expf(q1.x); c[1] = (_Float16)__expf(q1.y);
            er1[2 * k4] = c;
            c[0] = (_Float16)__expf(q1.z); c[1] = (_Float16)__expf(q1.w);
            er1[2 * k4 + 1] = c;
        }

        // init at u=511: beta_511 = 0 ; v = beta + em_511
        float2 e0 = *(const float2*)(em + base + (size_t)(L_ - 1) * N_ + 2 * l);
        float b0 = 0.f, b1 = 0.f;
        float v0 = e0.x, v1 = e0.y;
        float Mprev = wave_max(fmaxf(v0, v1));
        {
            h2_t eo;
            eo[0] = (_Float16)__expf(v0 - Mprev - C_BIAS);
            eo[1] = (_Float16)__expf(v1 - Mprev - C_BIAS);
            Eh[l] = eo;
        }

        float2 pipe0 = *(const float2*)(em + base + (size_t)510 * N_ + 2 * l);
        float2 pipe1 = *(const float2*)(em + base + (size_t)509 * N_ + 2 * l);
        float2 pipe2 = *(const float2*)(em + base + (size_t)508 * N_ + 2 * l);
        float2 pipe3 = *(const float2*)(em + base + (size_t)507 * N_ + 2 * l);

        // iter t (510 down to 255): consumes F_{t+1} (in Eh), em_t (pipe), mask_{t+1}
        auto step = [&](int t, float2& slot) {
            float2 emt = slot;
            int tpf = t - 4; if (tpf < TM - 1) tpf = TM - 1;
            slot = *(const float2*)(em + base + (size_t)tpf * N_ + 2 * l);
            float mk = Mlds[t + 1 - TM];

            float mx = wave_max(fmaxf(v0, v1));   // max(v_{t+1}); overlaps dots

            float a0 = 0.f, a1 = 0.f, a2 = 0.f, a3 = 0.f;
            float c0 = 0.f, c1 = 0.f, c2 = 0.f, c3 = 0.f;
            const float4* F4 = (const float4*)Eh;
#pragma unroll
            for (int r = 0; r < 16; ++r) {
                float4 blk = F4[r];
                const h2_t* f2 = (const h2_t*)&blk;
                a0 = dot2f(f2[0], er0[4 * r + 0], a0);
                a1 = dot2f(f2[1], er0[4 * r + 1], a1);
                a2 = dot2f(f2[2], er0[4 * r + 2], a2);
                a3 = dot2f(f2[3], er0[4 * r + 3], a3);
                c0 = dot2f(f2[0], er1[4 * r + 0], c0);
                c1 = dot2f(f2[1], er1[4 * r + 1], c1);
                c2 = dot2f(f2[2], er1[4 * r + 2], c2);
                c3 = dot2f(f2[3], er1[4 * r + 3], c3);
            }
            float s_0 = (a0 + a1) + (a2 + a3);
            float s_1 = (c0 + c1) + (c2 + c3);

            float badd = Mprev + C_BIAS;
            float upd0 = __logf(s_0) + badd;
            float upd1 = __logf(s_1) + badd;
            float im = 1.f - mk;
            b0 = mk * upd0 + im * b0;
            b1 = mk * upd1 + im * b1;

            v0 = b0 + emt.x;
            v1 = b1 + emt.y;
            Mprev = mx;
            h2_t eo;
            eo[0] = (_Float16)__expf(v0 - mx - C_BIAS);
            eo[1] = (_Float16)__expf(v1 - mx - C_BIAS);
            Eh[l] = eo;
        };

        for (int tt = 510; tt >= 258; tt -= 4) {   // 64 groups x 4 = t 510..255
            step(tt    , pipe0);
            step(tt - 1, pipe1);
            step(tt - 2, pipe2);
            step(tt - 3, pipe3);
        }

        *(float2*)(beta + b * N_ + 2 * l) = make_float2(b0, b1);
    }
}

// ---------------------------------------------------------------------------
// combine: Z_b = LSE_j(alpha[j]+beta[j]); out = mean(Z - pathf - pathb)
// one block, 16 waves; wave w handles batches [32w, 32w+32)
// ---------------------------------------------------------------------------
__global__ __launch_bounds__(1024) void combine_kernel(
    const float* __restrict__ alpha, const float* __restrict__ beta,
    const float* __restrict__ pathf, const float* __restrict__ pathb,
    float* __restrict__ out)
{
    __shared__ float part[16];
    const int tid = threadIdx.x;
    const int w = tid >> 6;
    const int l = tid & 63;
    float acc = 0.f;
    for (int k = 0; k < 32; ++k) {
        int b = w * 32 + k;
        float2 av = *(const float2*)(alpha + b * N_ + 2 * l);
        float2 bv = *(const float2*)(beta  + b * N_ + 2 * l);
        float v0 = av.x + bv.x;
        float v1 = av.y + bv.y;
        float m = wave_max(fmaxf(v0, v1));
        float s = wave_sum(__expf(v0 - m) + __expf(v1 - m));
        if (l == 0) acc += m + __logf(s) - pathf[b] - pathb[b];
    }
    if (l == 0) part[w] = acc;
    __syncthreads();
    if (tid == 0) {
        float t = 0.f;
#pragma unroll
        for (int i = 0; i < 16; ++i) t += part[i];
        out[0] = t / (float)B_;
    }
}

// ---------------------------------------------------------------------------
extern "C" void kernel_launch(void* const* d_in, const int* in_sizes, int n_in,
                              void* d_out, int out_size, void* d_ws, size_t ws_size,
                              hipStream_t stream) {
    const float* emission    = (const float*)d_in[0];
    const int*   target      = (const int*)  d_in[1];
    const float* mask        = (const float*)d_in[2];
    const float* start_trans = (const float*)d_in[3];
    const float* trans       = (const float*)d_in[4];
    float* out = (float*)d_out;

    float* ws_f  = (float*)d_ws;
    float* alpha = ws_f;                    // 512*128
    float* beta  = ws_f + B_ * N_;          // 512*128
    float* pathf = ws_f + 2 * B_ * N_;      // 512
    float* pathb = ws_f + 2 * B_ * N_ + B_; // 512

    norm_kernel   <<<2 * B_, 64, 0, stream>>>(emission, target, mask, start_trans,
                                              trans, alpha, beta, pathf, pathb);
    combine_kernel<<<1, 1024, 0, stream>>>(alpha, beta, pathf, pathb, out);
}